// Round 1
// baseline (370.200 us; speedup 1.0000x reference)
//
#include <hip/hip_runtime.h>

// Problem dims (fixed by reference setup_inputs): B=8, S=128, R=192, C=192.
// Reference collapses to a 7-point stencil on the index-clamped field
//   p(i,j,k) = batch_P[b, clamp(i,1,S-2), clamp(j,1,R-2), clamp(k,1,C-2)]
//   F  = sum_axis ((p(+1)-p(-1))/(2d))^2
//   G  = sum_axis  (p(+1)-2p(0)+p(-1))/d^2
//   out = -0.5*F - D*G
// (boundary cases verified by hand against _set_bc_neumann + edge-padded
//  _dc/_df/_db composition; clamped Laplacian is identically 0 at i=0,n-1
//  exactly like _db(_df) with edge padding)

#define BB 8
#define SS 128
#define RR 192
#define CC 192

__device__ __forceinline__ int clamp1(int x, int hi) {
    return min(max(x, 1), hi);
}

__global__ __launch_bounds__(256) void flowp_kernel(
    const float* __restrict__ P,
    const float* __restrict__ D,
    float* __restrict__ out)
{
    // SPACING = (2.0, 1.5, 1.5) for axes (S, R, C)
    const float inv2dx = 0.25f;                 // 1/(2*2.0)
    const float inv2dy = 1.0f / 3.0f;           // 1/(2*1.5)
    const float inv2dz = 1.0f / 3.0f;
    const float invdx2 = 0.25f;                 // 1/(2.0^2)
    const float invdy2 = 1.0f / 2.25f;          // 1/(1.5^2)
    const float invdz2 = 1.0f / 2.25f;

    const int total = BB * SS * RR * CC;
    int idx = blockIdx.x * blockDim.x + threadIdx.x;
    if (idx >= total) return;

    int k  = idx % CC;
    int t1 = idx / CC;
    int j  = t1 % RR;
    int t2 = t1 / RR;
    int i  = t2 % SS;
    int b  = t2 / SS;

    // clamped indices into batch_P
    const int ci  = clamp1(i,     SS - 2);
    const int cim = clamp1(i - 1, SS - 2);
    const int cip = clamp1(i + 1, SS - 2);
    const int cj  = clamp1(j,     RR - 2);
    const int cjm = clamp1(j - 1, RR - 2);
    const int cjp = clamp1(j + 1, RR - 2);
    const int ck  = clamp1(k,     CC - 2);
    const int ckm = clamp1(k - 1, CC - 2);
    const int ckp = clamp1(k + 1, CC - 2);

    const int bo = b * SS;
    const int rowc = ((bo + ci) * RR + cj) * CC;   // row of the (clamped) center

    const float pc  = P[rowc + ck];
    const float pCm = P[rowc + ckm];
    const float pCp = P[rowc + ckp];
    const float pSm = P[((bo + cim) * RR + cj) * CC + ck];
    const float pSp = P[((bo + cip) * RR + cj) * CC + ck];
    const float pRm = P[((bo + ci) * RR + cjm) * CC + ck];
    const float pRp = P[((bo + ci) * RR + cjp) * CC + ck];

    const float dcx = (pSp - pSm) * inv2dx;
    const float dcy = (pRp - pRm) * inv2dy;
    const float dcz = (pCp - pCm) * inv2dz;
    const float F = dcx * dcx + dcy * dcy + dcz * dcz;

    const float G = (pSp - 2.0f * pc + pSm) * invdx2
                  + (pRp - 2.0f * pc + pRm) * invdy2
                  + (pCp - 2.0f * pc + pCm) * invdz2;

    const float d = D[idx];
    out[idx] = -0.5f * F - d * G;
}

extern "C" void kernel_launch(void* const* d_in, const int* in_sizes, int n_in,
                              void* d_out, int out_size, void* d_ws, size_t ws_size,
                              hipStream_t stream) {
    // inputs: t (unused by reference), batch_P, D — all float32
    const float* P = (const float*)d_in[1];
    const float* D = (const float*)d_in[2];
    float* out = (float*)d_out;

    const int total = BB * SS * RR * CC;
    const int threads = 256;
    const int blocks = (total + threads - 1) / threads;
    flowp_kernel<<<blocks, threads, 0, stream>>>(P, D, out);
}

// Round 3
// 341.439 us; speedup vs baseline: 1.0842x; 1.0842x over previous
//
#include <hip/hip_runtime.h>

// B=8, S=128, R=192, C=192. 7-point stencil on the index-clamped field
//   p(i,j,k) = batch_P[b, clamp(i,1,S-2), clamp(j,1,R-2), clamp(k,1,C-2)]
//   out = -0.5 * sum((p(+1)-p(-1))/(2d))^2  -  D * sum((p(+1)-2p+p(-1))/d^2)
// Round-1 scalar version passed (absmax 0.031 vs thr 0.234) but was VALU-bound
// (VALUBusy 70%, HBM 2.76 TB/s). This version: float4 along C, 3D launch (no
// div/mod), branchless k-edge fixups, nt store for out / nt load for D.
// Round-2 fix: __builtin_nontemporal_* requires a native clang vector type,
// not HIP_vector_type — use ext_vector_type(4).

#define BB 8
#define SS 128
#define RR 192
#define CC 192

typedef float v4f __attribute__((ext_vector_type(4)));

__device__ __forceinline__ float stencil_pt(float pc, float pSm, float pSp,
                                            float pRm, float pRp,
                                            float pCm, float pCp, float d)
{
    const float inv2dx = 0.25f;        // 1/(2*2.0)
    const float inv2dy = 1.0f / 3.0f;  // 1/(2*1.5)
    const float inv2dz = 1.0f / 3.0f;
    const float invdx2 = 0.25f;        // 1/4.0
    const float invdy2 = 1.0f / 2.25f;
    const float invdz2 = 1.0f / 2.25f;

    float dcx = (pSp - pSm) * inv2dx;
    float dcy = (pRp - pRm) * inv2dy;
    float dcz = (pCp - pCm) * inv2dz;
    float F = dcx * dcx + dcy * dcy + dcz * dcz;
    float G = (pSp - 2.0f * pc + pSm) * invdx2
            + (pRp - 2.0f * pc + pRm) * invdy2
            + (pCp - 2.0f * pc + pCm) * invdz2;
    return -0.5f * F - d * G;
}

// block = (48, 4): tx covers the C axis in float4 chunks, ty covers 4 rows.
// grid = (1, R/4, B*S).
__global__ __launch_bounds__(192) void flowp_kernel(
    const float* __restrict__ P,
    const float* __restrict__ D,
    float* __restrict__ out)
{
    const int tx = threadIdx.x;              // 0..47
    const int k0 = tx << 2;                  // 0,4,...,188
    const int j  = blockIdx.y * 4 + threadIdx.y;  // 0..191
    const int bz = blockIdx.z;               // 0..1023
    const int i  = bz & (SS - 1);
    const int b  = bz >> 7;

    // clamped plane/row indices
    const int ci  = min(max(i,     1), SS - 2);
    const int cim = min(max(i - 1, 1), SS - 2);
    const int cip = min(max(i + 1, 1), SS - 2);
    const int cj  = min(max(j,     1), RR - 2);
    const int cjm = min(max(j - 1, 1), RR - 2);
    const int cjp = min(max(j + 1, 1), RR - 2);

    const int bS = b * SS;
    const int rowC  = ((bS + ci ) * RR + cj ) * CC;
    const int rowSm = ((bS + cim) * RR + cj ) * CC;
    const int rowSp = ((bS + cip) * RR + cj ) * CC;
    const int rowRm = ((bS + ci ) * RR + cjm) * CC;
    const int rowRp = ((bS + ci ) * RR + cjp) * CC;

    const bool e0 = (tx == 0);
    const bool e1 = (tx == 47);

    // center row: logical 6-window w[m] = P[rowC + clamp(k0-1+m, 1, C-2)]
    const v4f c4 = *(const v4f*)(P + rowC + k0);
    const int cmI = e0 ? 1      : k0 - 1;
    const int cpI = e1 ? CC - 2 : k0 + 4;
    const float cm = P[rowC + cmI];
    const float cp = P[rowC + cpI];
    // fixups: tx==0 -> w1 (P0) must be P1; tx==47 -> w4 (P191) must be P190
    const float w1 = e0 ? c4.y : c4.x;
    const float w2 = c4.y;
    const float w3 = c4.z;
    const float w4 = e1 ? c4.z : c4.w;

    // neighbor rows: need n[e] = P[row + clamp(k0+e, 1, C-2)], e = 0..3
    v4f nSm = *(const v4f*)(P + rowSm + k0);
    v4f nSp = *(const v4f*)(P + rowSp + k0);
    v4f nRm = *(const v4f*)(P + rowRm + k0);
    v4f nRp = *(const v4f*)(P + rowRp + k0);
    nSm.x = e0 ? nSm.y : nSm.x;  nSm.w = e1 ? nSm.z : nSm.w;
    nSp.x = e0 ? nSp.y : nSp.x;  nSp.w = e1 ? nSp.z : nSp.w;
    nRm.x = e0 ? nRm.y : nRm.x;  nRm.w = e1 ? nRm.z : nRm.w;
    nRp.x = e0 ? nRp.y : nRp.x;  nRp.w = e1 ? nRp.z : nRp.w;

    const int idxO = ((bS + i) * RR + j) * CC + k0;   // unclamped
    const v4f d4 = __builtin_nontemporal_load((const v4f*)(D + idxO));

    v4f o;
    //            pc  pSm    pSp    pRm    pRp    pCm  pCp  d
    o.x = stencil_pt(w1, nSm.x, nSp.x, nRm.x, nRp.x, cm, w2, d4.x);
    o.y = stencil_pt(w2, nSm.y, nSp.y, nRm.y, nRp.y, w1, w3, d4.y);
    o.z = stencil_pt(w3, nSm.z, nSp.z, nRm.z, nRp.z, w2, w4, d4.z);
    o.w = stencil_pt(w4, nSm.w, nSp.w, nRm.w, nRp.w, w3, cp, d4.w);

    __builtin_nontemporal_store(o, (v4f*)(out + idxO));
}

extern "C" void kernel_launch(void* const* d_in, const int* in_sizes, int n_in,
                              void* d_out, int out_size, void* d_ws, size_t ws_size,
                              hipStream_t stream) {
    const float* P = (const float*)d_in[1];
    const float* D = (const float*)d_in[2];
    float* out = (float*)d_out;

    dim3 block(48, 4, 1);                 // 192 threads = 3 waves
    dim3 grid(1, RR / 4, BB * SS);        // 48 x 1024 blocks
    flowp_kernel<<<grid, block, 0, stream>>>(P, D, out);
}